// Round 24
// baseline (1592.591 us; speedup 1.0000x reference)
//
#include <hip/hip_runtime.h>
#include <hip/hip_bf16.h>

// ---------------------------------------------------------------------------
// VQ-VAE forward — R24 (R23 @1591 ~= R20 @1576 noise; bn_tanh hoist null).
//  * fused_conv2: h1 stored as parity-split float4 cells h1p[16][9][9]
//    (cell y>>1,x>>1; lane (y&1)*2+(x&1)). Conv2 taps become 4 contiguous
//    b128 reads (was 16 even-stride b32 with 4-way conflicts = ~20% of
//    kernel). Values + FMA order bit-identical. LDS 38.0KB (== R20 occ).
//  * Everything else R23-exact.
// ---------------------------------------------------------------------------

#define EPS 1e-5

__global__ void zero_stats_k(double* s, int n) {
    int i = blockIdx.x * blockDim.x + threadIdx.x;
    if (i < n) s[i] = 0.0;
}

__global__ void convert_w_k(const float* __restrict__ w1, const float* __restrict__ w2,
                            const float* __restrict__ w3, double* __restrict__ w64) {
    int i = blockIdx.x * blockDim.x + threadIdx.x;
    if (i < 768) w64[i] = (double)w1[i];
    else if (i < 768 + 8192) w64[i] = (double)w2[i - 768];
    else if (i < 768 + 8192 + 32768) w64[i] = (double)w3[i - 768 - 8192];
}

__global__ void reduce_p_k(const double* __restrict__ p, int nblk, int c2,
                           double* __restrict__ dst) {
    int slot = blockIdx.x;
    double s = 0.0;
    for (int j = threadIdx.x; j < nblk; j += 256)
        s += p[(size_t)j * c2 + slot];
#pragma unroll
    for (int o = 32; o; o >>= 1) s += __shfl_down(s, o);
    __shared__ double ls[4];
    int wid = threadIdx.x >> 6, lane = threadIdx.x & 63;
    if (lane == 0) ls[wid] = s;
    __syncthreads();
    if (threadIdx.x == 0) dst[slot] = ls[0] + ls[1] + ls[2] + ls[3];
}

// ---- conv1 stats: f32 xs (R20-exact). grid(32,64), block 256 ----
__global__ void conv1_stats_k(const float* __restrict__ x, const double* __restrict__ w64,
                              const float* __restrict__ bias,
                              double* __restrict__ partials) {
    __shared__ float xs[3][6][258];
    __shared__ double lsw[4][32];
    int band = blockIdx.x, n = blockIdx.y, tid = threadIdx.x;
    double sums[16], sqs[16];
#pragma unroll
    for (int j = 0; j < 16; ++j) { sums[j] = 0.0; sqs[j] = 0.0; }
    for (int s8 = 0; s8 < 2; ++s8) {
        int strip = band * 2 + s8;
        int iyBase = 4 * strip - 1;
        __syncthreads();
        for (int idx = tid; idx < 3 * 6 * 258; idx += 256) {
            int ch = idx / 1548, rem = idx - ch * 1548, r = rem / 258, cc = rem - r * 258;
            int iy = iyBase + r, ix = cc - 1;
            float v = 0.f;
            if ((unsigned)iy < 256u && (unsigned)ix < 256u)
                v = x[(size_t)(n * 3 + ch) * 65536 + iy * 256 + ix];
            xs[ch][r][cc] = v;
        }
        __syncthreads();
        int lr = 2 * (tid >> 7), lc = 2 * (tid & 127);
        double xd[3][4][4];
#pragma unroll
        for (int ci = 0; ci < 3; ++ci)
#pragma unroll
            for (int ky = 0; ky < 4; ++ky)
#pragma unroll
                for (int kx = 0; kx < 4; ++kx)
                    xd[ci][ky][kx] = (double)xs[ci][lr + ky][lc + kx];
#pragma unroll
        for (int co = 0; co < 16; ++co) {
            double acc = (double)bias[co];
            const double* wp = w64 + co * 48;
#pragma unroll
            for (int ci = 0; ci < 3; ++ci)
#pragma unroll
                for (int ky = 0; ky < 4; ++ky)
#pragma unroll
                    for (int kx = 0; kx < 4; ++kx)
                        acc = fma(xd[ci][ky][kx], wp[ci * 16 + ky * 4 + kx], acc);
            sums[co] += acc;
            sqs[co] = fma(acc, acc, sqs[co]);
        }
    }
    double val[32];
#pragma unroll
    for (int j = 0; j < 16; ++j) { val[j] = sums[j]; val[16 + j] = sqs[j]; }
#pragma unroll
    for (int o = 32; o; o >>= 1)
#pragma unroll
        for (int j = 0; j < 32; ++j) val[j] += __shfl_down(val[j], o);
    int wid = tid >> 6, lane = tid & 63;
    if (lane == 0)
#pragma unroll
        for (int j = 0; j < 32; ++j) lsw[wid][j] = val[j];
    __syncthreads();
    if (tid < 32) {
        double p = lsw[0][tid] + lsw[1][tid] + lsw[2][tid] + lsw[3][tid];
        partials[(size_t)(n * 32 + band) * 32 + tid] = p;
    }
}

// ---- fused conv1+BN1+ReLU -> conv2 -> h2 + stats. grid(64,64), block 512 ----
// h1 in parity-split float4 cells: h1p[ci][y>>1][x>>1] lane (y&1)*2+(x&1).
__global__ void fused_conv2_k(const float* __restrict__ x, const double* __restrict__ w1_64,
                              const float* __restrict__ eb1, const float* __restrict__ eg1,
                              const float* __restrict__ ebt1, const double* __restrict__ w2_64,
                              const float* __restrict__ eb2, const double* __restrict__ stats,
                              float* __restrict__ h2, double* __restrict__ ph2) {
    __shared__ float xs[3][38][38];
    __shared__ float4 h1p[16][9][9];
    int tile = blockIdx.x, n = blockIdx.y, tid = threadIdx.x;
    int ty = tile >> 3, tx = tile & 7;
    int iyBase = 32 * ty - 3, ixBase = 32 * tx - 3;
    for (int idx = tid; idx < 3 * 38 * 38; idx += 512) {
        int ch = idx / 1444, rem = idx - ch * 1444, r = rem / 38, cc = rem - r * 38;
        int iy = iyBase + r, ix = ixBase + cc;
        float v = 0.f;
        if ((unsigned)iy < 256u && (unsigned)ix < 256u)
            v = x[(size_t)(n * 3 + ch) * 65536 + iy * 256 + ix];
        xs[ch][r][cc] = v;
    }
    __syncthreads();
    int hy0 = 16 * ty - 1, hx0 = 16 * tx - 1;
    for (int idx = tid; idx < 16 * 18 * 18; idx += 512) {
        int ci = idx / 324, rem = idx - ci * 324, r = rem / 18, cc = rem - r * 18;
        int hy = hy0 + r, hx = hx0 + cc;
        float val = 0.f;
        if ((unsigned)hy < 128u && (unsigned)hx < 128u) {
            double xd[3][4][4];
#pragma unroll
            for (int c3 = 0; c3 < 3; ++c3)
#pragma unroll
                for (int ky = 0; ky < 4; ++ky)
#pragma unroll
                    for (int kx = 0; kx < 4; ++kx)
                        xd[c3][ky][kx] = (double)xs[c3][2 * r + ky][2 * cc + kx];
            double acc = (double)eb1[ci];
            const double* wp = w1_64 + ci * 48;
#pragma unroll
            for (int c3 = 0; c3 < 3; ++c3)
#pragma unroll
                for (int ky = 0; ky < 4; ++ky)
#pragma unroll
                    for (int kx = 0; kx < 4; ++kx)
                        acc = fma(xd[c3][ky][kx], wp[c3 * 16 + ky * 4 + kx], acc);
            double m = stats[ci] * (1.0 / 1048576.0);
            double var = stats[16 + ci] * (1.0 / 1048576.0) - m * m;
            double sc = (double)eg1[ci] / sqrt(var + EPS);
            double sh = (double)ebt1[ci] - m * sc;
            double v = fma(acc, sc, sh);
            val = (float)(v > 0.0 ? v : 0.0);
        }
        ((float*)&h1p[ci][r >> 1][cc >> 1])[(r & 1) * 2 + (cc & 1)] = val;
    }
    __syncthreads();
    int s = tid & 63, ly = s >> 3, lx = s & 7;
    int cog = __builtin_amdgcn_readfirstlane((tid >> 6) * 4);  // 8 waves x 4 co
    double acc[4];
#pragma unroll
    for (int j = 0; j < 4; ++j) acc[j] = (double)eb2[cog + j];
    for (int ci = 0; ci < 16; ++ci) {
        float4 c00 = h1p[ci][ly][lx];
        float4 c01 = h1p[ci][ly][lx + 1];
        float4 c10 = h1p[ci][ly + 1][lx];
        float4 c11 = h1p[ci][ly + 1][lx + 1];
        // td[ky*4+kx]: y=2ly+ky -> cell a=ky>>1, lane py=ky&1; x analogous.
        double td[16];
        td[0]  = (double)c00.x;  td[1]  = (double)c00.y;
        td[2]  = (double)c01.x;  td[3]  = (double)c01.y;
        td[4]  = (double)c00.z;  td[5]  = (double)c00.w;
        td[6]  = (double)c01.z;  td[7]  = (double)c01.w;
        td[8]  = (double)c10.x;  td[9]  = (double)c10.y;
        td[10] = (double)c11.x;  td[11] = (double)c11.y;
        td[12] = (double)c10.z;  td[13] = (double)c10.w;
        td[14] = (double)c11.z;  td[15] = (double)c11.w;
#pragma unroll
        for (int j = 0; j < 4; ++j) {
            const double* wp = w2_64 + ((cog + j) * 16 + ci) * 16;
#pragma unroll
            for (int k = 0; k < 16; ++k)
                acc[j] = fma(td[k], wp[k], acc[j]);
        }
    }
    int oy = 8 * ty + ly, ox = 8 * tx + lx;
    double s4[4], q4[4];
#pragma unroll
    for (int j = 0; j < 4; ++j) {
        float f = (float)acc[j];
        h2[(size_t)(n * 32 + cog + j) * 4096 + oy * 64 + ox] = f;
        double v = (double)f;
        s4[j] = v;
        q4[j] = v * v;
    }
#pragma unroll
    for (int o = 32; o; o >>= 1)
#pragma unroll
        for (int j = 0; j < 4; ++j) {
            s4[j] += __shfl_down(s4[j], o);
            q4[j] += __shfl_down(q4[j], o);
        }
    if (s == 0) {
        size_t blk = (size_t)(n * 64 + tile) * 64;
#pragma unroll
        for (int j = 0; j < 4; ++j) {
            ph2[blk + cog + j] = s4[j];
            ph2[blk + 32 + cog + j] = q4[j];
        }
    }
}

__device__ __forceinline__ void bn_consts(int tid, int C, const double* sum,
                                          const double* sq, const float* g,
                                          const float* b, double invCnt,
                                          double* scd, double* shd) {
    if (tid < C) {
        double m = sum[tid] * invCnt;
        double var = sq[tid] * invCnt - m * m;
        double sc = (double)g[tid] / sqrt(var + EPS);
        scd[tid] = sc;
        shd[tid] = (double)b[tid] - m * sc;
    }
}

// ---- conv3: BN2+ReLU(h2) staged -> z + stats. grid(16,64), block 512 ----
__global__ void conv3_k(const float* __restrict__ h2, const double* __restrict__ w3_64,
                        const float* __restrict__ bias, const float* __restrict__ eg2,
                        const float* __restrict__ ebt2, const double* __restrict__ sum2,
                        const double* __restrict__ sq2, float* __restrict__ z3,
                        double* __restrict__ pz) {
    __shared__ float hs[32][6][66];
    __shared__ double scd[32], shd[32];
    int c = blockIdx.x, n = blockIdx.y, tid = threadIdx.x;
    bn_consts(tid, 32, sum2, sq2, eg2, ebt2, 1.0 / 262144.0, scd, shd);
    __syncthreads();
    int iyBase = 4 * c - 1;
    for (int idx = tid; idx < 32 * 6 * 66; idx += 512) {
        int ch = idx / 396, rem = idx - ch * 396, r = rem / 66, cc = rem - r * 66;
        int iy = iyBase + r, ix = cc - 1;
        float val = 0.f;
        if ((unsigned)iy < 64u && (unsigned)ix < 64u) {
            double v = fma((double)h2[(size_t)(n * 32 + ch) * 4096 + iy * 64 + ix],
                           scd[ch], shd[ch]);
            val = v > 0.0 ? (float)v : 0.f;
        }
        hs[ch][r][cc] = val;
    }
    __syncthreads();
    int s = tid & 63;
    int oy = 2 * c + (s >> 5), ox = s & 31;
    int lr = 2 * (s >> 5), lc = 2 * ox;
    int cog = __builtin_amdgcn_readfirstlane((tid >> 6) * 8);
    double acc[8];
#pragma unroll
    for (int j = 0; j < 8; ++j) acc[j] = (double)bias[cog + j];
    for (int ci = 0; ci < 32; ++ci) {
        double td[16];
#pragma unroll
        for (int ky = 0; ky < 4; ++ky)
#pragma unroll
            for (int kx = 0; kx < 4; ++kx)
                td[ky * 4 + kx] = (double)hs[ci][lr + ky][lc + kx];
#pragma unroll
        for (int j = 0; j < 8; ++j) {
            const double* wp = w3_64 + ((cog + j) * 32 + ci) * 16;
#pragma unroll
            for (int k = 0; k < 16; ++k)
                acc[j] = fma(td[k], wp[k], acc[j]);
        }
    }
    double s8[8], q8[8];
#pragma unroll
    for (int j = 0; j < 8; ++j) {
        float f = (float)acc[j];
        z3[(size_t)(n * 64 + cog + j) * 1024 + oy * 32 + ox] = f;
        double v = (double)f;
        s8[j] = v;
        q8[j] = v * v;
    }
#pragma unroll
    for (int o = 32; o; o >>= 1)
#pragma unroll
        for (int j = 0; j < 8; ++j) {
            s8[j] += __shfl_down(s8[j], o);
            q8[j] += __shfl_down(q8[j], o);
        }
    if (s == 0) {
        size_t blk = (size_t)(n * 16 + c) * 128;
#pragma unroll
        for (int j = 0; j < 8; ++j) {
            pz[blk + cog + j] = s8[j];
            pz[blk + 64 + cog + j] = q8[j];
        }
    }
}

__device__ __forceinline__ float np_sum64(const float* a) {
    float r[8];
#pragma unroll
    for (int j = 0; j < 8; ++j) r[j] = a[j];
#pragma unroll
    for (int m = 1; m < 8; ++m)
#pragma unroll
        for (int j = 0; j < 8; ++j) r[j] += a[m * 8 + j];
    return ((r[0] + r[1]) + (r[2] + r[3])) + ((r[4] + r[5]) + (r[6] + r[7]));
}

__global__ void scc_k(const float* __restrict__ cb, float* __restrict__ scc) {
    int k = blockIdx.x * blockDim.x + threadIdx.x;
    if (k >= 512) return;
    const float* c = cb + (k << 6);
    float cc[64];
#pragma unroll
    for (int d = 0; d < 64; ++d) cc[d] = c[d] * c[d];
    scc[k] = np_sum64(cc);
}

// ---- VQ: 4-way k-chunk. grid(1024), block 256 ----
__global__ void vq_k(const float* __restrict__ zraw, const float* __restrict__ cb,
                     const float* __restrict__ scc, const float* __restrict__ eg3,
                     const float* __restrict__ ebt3, const double* __restrict__ sum3,
                     const double* __restrict__ sq3, float* __restrict__ quant,
                     double* __restrict__ lossAcc) {
    __shared__ double scd[64], shd[64];
    __shared__ float bfs[256];
    __shared__ int bis[256];
    bn_consts(threadIdx.x, 64, sum3, sq3, eg3, ebt3, 1.0 / 65536.0, scd, shd);
    __syncthreads();
    int chunk = threadIdx.x >> 6, pi = threadIdx.x & 63;
    int p = blockIdx.x * 64 + pi;
    int n = p >> 10, hw = p & 1023;
    const float* zp = zraw + (size_t)n * 65536 + hw;
    float z32[64], zz[64];
#pragma unroll
    for (int d = 0; d < 64; ++d) {
        double v = fma((double)zp[d * 1024], scd[d], shd[d]);
        z32[d] = v > 0.0 ? (float)v : 0.f;
        zz[d] = z32[d] * z32[d];
    }
    float sz = np_sum64(zz);
    int k0 = chunk << 7;
    float bestf = 3.4e38f;
    int bif = k0;
    for (int k = k0; k < k0 + 128; ++k) {
        const float* c = cb + (k << 6);
        float dot = 0.f;
#pragma unroll
        for (int d = 0; d < 64; ++d) dot = fmaf(z32[d], c[d], dot);
        float distf = (sz + scc[k]) - 2.f * dot;
        if (distf < bestf) { bestf = distf; bif = k; }
    }
    bfs[threadIdx.x] = bestf;
    bis[threadIdx.x] = bif;
    __syncthreads();
    if (chunk == 0) {
#pragma unroll
        for (int c4 = 1; c4 < 4; ++c4) {
            float v = bfs[c4 * 64 + pi];
            if (v < bestf) { bestf = v; bif = bis[c4 * 64 + pi]; }
        }
        const float* c = cb + (bif << 6);
        float* qp = quant + (size_t)n * 65536 + hw;
        double dist = 0.0;
#pragma unroll
        for (int d = 0; d < 64; ++d) {
            double diff = (double)z32[d] - (double)c[d];
            dist = fma(diff, diff, dist);
            qp[d * 1024] = c[d];
        }
        double s = dist;
#pragma unroll
        for (int o = 32; o; o >>= 1) s += __shfl_down(s, o);
        if (pi == 0) atomicAdd(lossAcc, s);
    }
}

__global__ void finalize_loss_k(const double* lossAcc, float* out, int idx) {
    if (threadIdx.x == 0 && blockIdx.x == 0)
        out[idx] = (float)(2.0 * (*lossAcc) / 4194304.0);
}

// ---- deconv1 + stats. grid(16,64), block 512: 8 waves x 4 co ----
__global__ void deconv1_k(const float* __restrict__ in, const float* __restrict__ w,
                          const float* __restrict__ bias, float* __restrict__ out,
                          double* __restrict__ pd1) {
    __shared__ float ls[64][4][34];
    int b = blockIdx.x, n = blockIdx.y, tid = threadIdx.x;
    int qy0 = 2 * b;
    for (int idx = tid; idx < 64 * 4 * 34; idx += 512) {
        int ch = idx / 136, rem = idx - ch * 136, r = rem / 34, cc = rem - r * 34;
        int iy = qy0 - 1 + r, ix = cc - 1;
        float v = 0.f;
        if ((unsigned)iy < 32u && (unsigned)ix < 32u)
            v = in[(size_t)(n * 64 + ch) * 1024 + iy * 32 + ix];
        ls[ch][r][cc] = v;
    }
    __syncthreads();
    int pt = tid & 63;
    int qy = qy0 + (pt >> 5), qx = pt & 31;
    int cog = (tid >> 6) * 4;
    int rb = qy - qy0;
    float acc[2][2][4];
#pragma unroll
    for (int dy = 0; dy < 2; ++dy)
#pragma unroll
        for (int dx = 0; dx < 2; ++dx)
#pragma unroll
            for (int j = 0; j < 4; ++j) acc[dy][dx][j] = bias[cog + j];
    for (int ci = 0; ci < 64; ++ci) {
        float v[3][3];
#pragma unroll
        for (int ry = 0; ry < 3; ++ry)
#pragma unroll
            for (int rx = 0; rx < 3; ++rx)
                v[ry][rx] = ls[ci][rb + ry][qx + rx];
#pragma unroll
        for (int j = 0; j < 4; ++j) {
            const float* wp = w + ((cog + j) * 64 + ci) * 16;
            acc[0][0][j] += v[0][0]*wp[0] + v[0][1]*wp[2] + v[1][0]*wp[8]  + v[1][1]*wp[10];
            acc[0][1][j] += v[0][1]*wp[1] + v[0][2]*wp[3] + v[1][1]*wp[9]  + v[1][2]*wp[11];
            acc[1][0][j] += v[1][0]*wp[4] + v[1][1]*wp[6] + v[2][0]*wp[12] + v[2][1]*wp[14];
            acc[1][1][j] += v[1][1]*wp[5] + v[1][2]*wp[7] + v[2][1]*wp[13] + v[2][2]*wp[15];
        }
    }
    double s4[4], q4[4];
#pragma unroll
    for (int j = 0; j < 4; ++j) { s4[j] = 0.0; q4[j] = 0.0; }
#pragma unroll
    for (int dy = 0; dy < 2; ++dy)
#pragma unroll
        for (int dx = 0; dx < 2; ++dx)
#pragma unroll
            for (int j = 0; j < 4; ++j) {
                float f = acc[dy][dx][j];
                out[(size_t)(n * 32 + cog + j) * 4096 + (2*qy+dy) * 64 + 2*qx+dx] = f;
                double v = (double)f;
                s4[j] += v;
                q4[j] = fma(v, v, q4[j]);
            }
#pragma unroll
    for (int o = 32; o; o >>= 1)
#pragma unroll
        for (int j = 0; j < 4; ++j) {
            s4[j] += __shfl_down(s4[j], o);
            q4[j] += __shfl_down(q4[j], o);
        }
    if (pt == 0) {
        size_t blk = (size_t)(n * 16 + b) * 64;
#pragma unroll
        for (int j = 0; j < 4; ++j) {
            pd1[blk + cog + j] = s4[j];
            pd1[blk + 32 + cog + j] = q4[j];
        }
    }
}

// ---- deconv2: BN4+ReLU(d1) staged + stats. grid(64,64), block 512 ----
__global__ void deconv2_k(const float* __restrict__ in, const float* __restrict__ w,
                          const float* __restrict__ bias, const float* __restrict__ g,
                          const float* __restrict__ bt, const double* __restrict__ sum,
                          const double* __restrict__ sq, float* __restrict__ out,
                          double* __restrict__ pd2) {
    __shared__ float ls[32][3][66];
    __shared__ double scd[32], shd[32];
    int b = blockIdx.x, n = blockIdx.y, tid = threadIdx.x;
    bn_consts(tid, 32, sum, sq, g, bt, 1.0 / 262144.0, scd, shd);
    __syncthreads();
    for (int idx = tid; idx < 32 * 3 * 66; idx += 512) {
        int ch = idx / 198, rem = idx - ch * 198, r = rem / 66, cc = rem - r * 66;
        int iy = b - 1 + r, ix = cc - 1;
        float val = 0.f;
        if ((unsigned)iy < 64u && (unsigned)ix < 64u) {
            double v = fma((double)in[(size_t)(n * 32 + ch) * 4096 + iy * 64 + ix],
                           scd[ch], shd[ch]);
            val = v > 0.0 ? (float)v : 0.f;
        }
        ls[ch][r][cc] = val;
    }
    __syncthreads();
    int qx = tid & 63;
    int cog = (tid >> 6) * 2;
    float acc[2][2][2];
#pragma unroll
    for (int dy = 0; dy < 2; ++dy)
#pragma unroll
        for (int dx = 0; dx < 2; ++dx)
#pragma unroll
            for (int j = 0; j < 2; ++j) acc[dy][dx][j] = bias[cog + j];
    for (int ci = 0; ci < 32; ++ci) {
        float v[3][3];
#pragma unroll
        for (int ry = 0; ry < 3; ++ry)
#pragma unroll
            for (int rx = 0; rx < 3; ++rx)
                v[ry][rx] = ls[ci][ry][qx + rx];
#pragma unroll
        for (int j = 0; j < 2; ++j) {
            const float* wp = w + ((cog + j) * 32 + ci) * 16;
            acc[0][0][j] += v[0][0]*wp[0] + v[0][1]*wp[2] + v[1][0]*wp[8]  + v[1][1]*wp[10];
            acc[0][1][j] += v[0][1]*wp[1] + v[0][2]*wp[3] + v[1][1]*wp[9]  + v[1][2]*wp[11];
            acc[1][0][j] += v[1][0]*wp[4] + v[1][1]*wp[6] + v[2][0]*wp[12] + v[2][1]*wp[14];
            acc[1][1][j] += v[1][1]*wp[5] + v[1][2]*wp[7] + v[2][1]*wp[13] + v[2][2]*wp[15];
        }
    }
    double s2[2], q2[2];
#pragma unroll
    for (int j = 0; j < 2; ++j) { s2[j] = 0.0; q2[j] = 0.0; }
#pragma unroll
    for (int dy = 0; dy < 2; ++dy)
#pragma unroll
        for (int dx = 0; dx < 2; ++dx)
#pragma unroll
            for (int j = 0; j < 2; ++j) {
                float f = acc[dy][dx][j];
                out[(size_t)(n * 16 + cog + j) * 16384 + (2*b+dy) * 128 + 2*qx+dx] = f;
                double v = (double)f;
                s2[j] += v;
                q2[j] = fma(v, v, q2[j]);
            }
#pragma unroll
    for (int o = 32; o; o >>= 1)
#pragma unroll
        for (int j = 0; j < 2; ++j) {
            s2[j] += __shfl_down(s2[j], o);
            q2[j] += __shfl_down(q2[j], o);
        }
    if (qx == 0) {
        size_t blk = (size_t)(n * 64 + b) * 32;
#pragma unroll
        for (int j = 0; j < 2; ++j) {
            pd2[blk + cog + j] = s2[j];
            pd2[blk + 16 + cog + j] = q2[j];
        }
    }
}

// ---- deconv3: BN5+ReLU(d2) staged -> raw into d_out + stats. grid(64,64),256 ----
__global__ void deconv3_k(const float* __restrict__ in, const float* __restrict__ w,
                          const float* __restrict__ bias, const float* __restrict__ g,
                          const float* __restrict__ bt, const double* __restrict__ sum,
                          const double* __restrict__ sq, float* __restrict__ out,
                          double* __restrict__ pd3) {
    __shared__ float ls[16][4][130];
    __shared__ double scd[16], shd[16];
    __shared__ double lsw[4][6];
    int b = blockIdx.x, n = blockIdx.y, tid = threadIdx.x;
    bn_consts(tid, 16, sum, sq, g, bt, 1.0 / 1048576.0, scd, shd);
    __syncthreads();
    int qy0 = 2 * b;
    for (int idx = tid; idx < 16 * 4 * 130; idx += 256) {
        int ch = idx / 520, rem = idx - ch * 520, r = rem / 130, cc = rem - r * 130;
        int iy = qy0 - 1 + r, ix = cc - 1;
        float val = 0.f;
        if ((unsigned)iy < 128u && (unsigned)ix < 128u) {
            double v = fma((double)in[(size_t)(n * 16 + ch) * 16384 + iy * 128 + ix],
                           scd[ch], shd[ch]);
            val = v > 0.0 ? (float)v : 0.f;
        }
        ls[ch][r][cc] = val;
    }
    __syncthreads();
    int qy = qy0 + (tid >> 7), qx = tid & 127;
    int rb = qy - qy0;
    float acc[2][2][3];
#pragma unroll
    for (int dy = 0; dy < 2; ++dy)
#pragma unroll
        for (int dx = 0; dx < 2; ++dx)
#pragma unroll
            for (int j = 0; j < 3; ++j) acc[dy][dx][j] = bias[j];
    for (int ci = 0; ci < 16; ++ci) {
        float v[3][3];
#pragma unroll
        for (int ry = 0; ry < 3; ++ry)
#pragma unroll
            for (int rx = 0; rx < 3; ++rx)
                v[ry][rx] = ls[ci][rb + ry][qx + rx];
#pragma unroll
        for (int j = 0; j < 3; ++j) {
            const float* wp = w + (j * 16 + ci) * 16;
            acc[0][0][j] += v[0][0]*wp[0] + v[0][1]*wp[2] + v[1][0]*wp[8]  + v[1][1]*wp[10];
            acc[0][1][j] += v[0][1]*wp[1] + v[0][2]*wp[3] + v[1][1]*wp[9]  + v[1][2]*wp[11];
            acc[1][0][j] += v[1][0]*wp[4] + v[1][1]*wp[6] + v[2][0]*wp[12] + v[2][1]*wp[14];
            acc[1][1][j] += v[1][1]*wp[5] + v[1][2]*wp[7] + v[2][1]*wp[13] + v[2][2]*wp[15];
        }
    }
    double s3[3], q3[3];
#pragma unroll
    for (int j = 0; j < 3; ++j) { s3[j] = 0.0; q3[j] = 0.0; }
#pragma unroll
    for (int dy = 0; dy < 2; ++dy)
#pragma unroll
        for (int dx = 0; dx < 2; ++dx)
#pragma unroll
            for (int j = 0; j < 3; ++j) {
                float f = acc[dy][dx][j];
                out[(size_t)(n * 3 + j) * 65536 + (2*qy+dy) * 256 + 2*qx+dx] = f;
                double v = (double)f;
                s3[j] += v;
                q3[j] = fma(v, v, q3[j]);
            }
#pragma unroll
    for (int o = 32; o; o >>= 1)
#pragma unroll
        for (int j = 0; j < 3; ++j) {
            s3[j] += __shfl_down(s3[j], o);
            q3[j] += __shfl_down(q3[j], o);
        }
    int wid = tid >> 6, lane = tid & 63;
    if (lane == 0)
#pragma unroll
        for (int j = 0; j < 3; ++j) { lsw[wid][j] = s3[j]; lsw[wid][3 + j] = q3[j]; }
    __syncthreads();
    if (tid < 6) {
        double p = lsw[0][tid] + lsw[1][tid] + lsw[2][tid] + lsw[3][tid];
        pd3[(size_t)(n * 64 + b) * 6 + tid] = p;
    }
}

// ---- final BN + tanh IN PLACE on d_out; constants hoisted per block ----
__global__ void bn_tanh_k(float* __restrict__ y, const double* __restrict__ sum,
                          const double* __restrict__ sq, const float* __restrict__ g,
                          const float* __restrict__ b, int HW, double invCnt) {
    __shared__ double cst[2];
    int c = blockIdx.y, n = blockIdx.z, C = gridDim.y;
    if (threadIdx.x == 0) {
        double m = sum[c] * invCnt;
        double var = sq[c] * invCnt - m * m;
        double sc = (double)g[c] / sqrt(var + EPS);
        cst[0] = sc;
        cst[1] = (double)b[c] - m * sc;
    }
    __syncthreads();
    int hw = blockIdx.x * blockDim.x + threadIdx.x;
    size_t i = (size_t)(n * C + c) * HW + hw;
    y[i] = tanhf((float)fma((double)y[i], cst[0], cst[1]));
}

extern "C" void kernel_launch(void* const* d_in, const int* in_sizes, int n_in,
                              void* d_out, int out_size, void* d_ws, size_t ws_size,
                              hipStream_t stream) {
    const float* x   = (const float*)d_in[0];
    const float* cb  = (const float*)d_in[1];
    const float* eW1 = (const float*)d_in[2];
    const float* eb1 = (const float*)d_in[3];
    const float* eg1 = (const float*)d_in[4];
    const float* ebt1= (const float*)d_in[5];
    const float* eW2 = (const float*)d_in[6];
    const float* eb2 = (const float*)d_in[7];
    const float* eg2 = (const float*)d_in[8];
    const float* ebt2= (const float*)d_in[9];
    const float* eW3 = (const float*)d_in[10];
    const float* eb3 = (const float*)d_in[11];
    const float* eg3 = (const float*)d_in[12];
    const float* ebt3= (const float*)d_in[13];
    const float* dW1 = (const float*)d_in[14];
    const float* db1 = (const float*)d_in[15];
    const float* dg1 = (const float*)d_in[16];
    const float* dbt1= (const float*)d_in[17];
    const float* dW2 = (const float*)d_in[18];
    const float* db2 = (const float*)d_in[19];
    const float* dg2 = (const float*)d_in[20];
    const float* dbt2= (const float*)d_in[21];
    const float* dW3 = (const float*)d_in[22];
    const float* db3 = (const float*)d_in[23];
    const float* dg3 = (const float*)d_in[24];
    const float* dbt3= (const float*)d_in[25];

    float* out = (float*)d_out;
    char* ws = (char*)d_ws;
    float* h2    = (float*)ws;                        // [0, 33.5M)
    float* z     = (float*)(ws + 33554432);           // [33.5M, 50.3M)
    float* quant = (float*)(ws + 50331648);           // [50.3M, 67.1M)
    float* d1    = (float*)(ws + 67108864);           // [67.1M, 100.7M)
    float* d2    = (float*)ws;                        // [0, 67.1M)
    double* partials = (double*)ws;                   // conv1, dead pre-h2
    double* w64  = (double*)(ws + 67108864);          // dead before d1
    double* w1_64 = w64;
    double* w2_64 = w64 + 768;
    double* w3_64 = w64 + 768 + 8192;
    double* ph2  = (double*)(ws + 50331648);          // 2MB, dead pre-vq-quant
    double* pz   = (double*)(ws + 52428800);          // 1MB, dead pre-vq-quant
    double* pd1  = (double*)ws;                       // 512KB, dead pre-d2
    double* pd2  = (double*)(ws + 100663296);         // 1MB, above d1 (free)
    double* pd3  = (double*)(ws + 67108864);          // 192KB, free post-deconv2
    double* stats = (double*)(ws + 117440512);        // 327 doubles
    double* lossAcc = stats + 326;
    float* scc   = (float*)(ws + 117443200);          // 512 f32
    dim3 B(256), B2(512);

    zero_stats_k<<<2, B, 0, stream>>>(stats, 327);
    scc_k<<<2, B, 0, stream>>>(cb, scc);
    convert_w_k<<<163, B, 0, stream>>>(eW1, eW2, eW3, w64);

    // encoder
    conv1_stats_k<<<dim3(32, 64), B, 0, stream>>>(x, w1_64, eb1, partials);
    reduce_p_k<<<32, B, 0, stream>>>(partials, 2048, 32, stats);
    fused_conv2_k<<<dim3(64, 64), B2, 0, stream>>>(x, w1_64, eb1, eg1, ebt1, w2_64,
                                                   eb2, stats, h2, ph2);
    reduce_p_k<<<64, B, 0, stream>>>(ph2, 4096, 64, stats + 32);
    conv3_k<<<dim3(16, 64), B2, 0, stream>>>(h2, w3_64, eb3, eg2, ebt2,
                                             stats + 32, stats + 64, z, pz);
    reduce_p_k<<<128, B, 0, stream>>>(pz, 1024, 128, stats + 96);
    vq_k<<<1024, B, 0, stream>>>(z, cb, scc, eg3, ebt3, stats + 96, stats + 160,
                                 quant, lossAcc);
    finalize_loss_k<<<1, 64, 0, stream>>>(lossAcc, out, out_size - 1);

    // decoder
    deconv1_k<<<dim3(16, 64), B2, 0, stream>>>(quant, dW1, db1, d1, pd1);
    reduce_p_k<<<64, B, 0, stream>>>(pd1, 1024, 64, stats + 224);
    deconv2_k<<<dim3(64, 64), B2, 0, stream>>>(d1, dW2, db2, dg1, dbt1,
                                               stats + 224, stats + 256, d2, pd2);
    reduce_p_k<<<32, B, 0, stream>>>(pd2, 4096, 32, stats + 288);
    deconv3_k<<<dim3(64, 64), B, 0, stream>>>(d2, dW3, db3, dg2, dbt2,
                                              stats + 288, stats + 304, out, pd3);
    reduce_p_k<<<6, B, 0, stream>>>(pd3, 4096, 6, stats + 320);
    bn_tanh_k<<<dim3(256, 3, 64), B, 0, stream>>>(out, stats + 320, stats + 323,
                                                  dg3, dbt3, 65536, 1.0 / 4194304.0);
}

// Round 25
// 1566.757 us; speedup vs baseline: 1.0165x; 1.0165x over previous
//
#include <hip/hip_runtime.h>
#include <hip/hip_bf16.h>

// ---------------------------------------------------------------------------
// VQ-VAE forward — R25 (R24 parity-split null; reverted to R20-form h1s).
//  * fused_conv2: BN1 constants hoisted to once-per-block LDS (was ~5184
//    f64 div+sqrt per block — one per h1 position, ci loop-variant so the
//    compiler can't hoist). Bit-identical (same ops, same inputs; shares
//    the existing staging barrier).
//  * Everything else R23-exact (best-known config, 1576-1592us band).
// ---------------------------------------------------------------------------

#define EPS 1e-5

__global__ void zero_stats_k(double* s, int n) {
    int i = blockIdx.x * blockDim.x + threadIdx.x;
    if (i < n) s[i] = 0.0;
}

__global__ void convert_w_k(const float* __restrict__ w1, const float* __restrict__ w2,
                            const float* __restrict__ w3, double* __restrict__ w64) {
    int i = blockIdx.x * blockDim.x + threadIdx.x;
    if (i < 768) w64[i] = (double)w1[i];
    else if (i < 768 + 8192) w64[i] = (double)w2[i - 768];
    else if (i < 768 + 8192 + 32768) w64[i] = (double)w3[i - 768 - 8192];
}

__global__ void reduce_p_k(const double* __restrict__ p, int nblk, int c2,
                           double* __restrict__ dst) {
    int slot = blockIdx.x;
    double s = 0.0;
    for (int j = threadIdx.x; j < nblk; j += 256)
        s += p[(size_t)j * c2 + slot];
#pragma unroll
    for (int o = 32; o; o >>= 1) s += __shfl_down(s, o);
    __shared__ double ls[4];
    int wid = threadIdx.x >> 6, lane = threadIdx.x & 63;
    if (lane == 0) ls[wid] = s;
    __syncthreads();
    if (threadIdx.x == 0) dst[slot] = ls[0] + ls[1] + ls[2] + ls[3];
}

// ---- conv1 stats: f32 xs (R20-exact). grid(32,64), block 256 ----
__global__ void conv1_stats_k(const float* __restrict__ x, const double* __restrict__ w64,
                              const float* __restrict__ bias,
                              double* __restrict__ partials) {
    __shared__ float xs[3][6][258];
    __shared__ double lsw[4][32];
    int band = blockIdx.x, n = blockIdx.y, tid = threadIdx.x;
    double sums[16], sqs[16];
#pragma unroll
    for (int j = 0; j < 16; ++j) { sums[j] = 0.0; sqs[j] = 0.0; }
    for (int s8 = 0; s8 < 2; ++s8) {
        int strip = band * 2 + s8;
        int iyBase = 4 * strip - 1;
        __syncthreads();
        for (int idx = tid; idx < 3 * 6 * 258; idx += 256) {
            int ch = idx / 1548, rem = idx - ch * 1548, r = rem / 258, cc = rem - r * 258;
            int iy = iyBase + r, ix = cc - 1;
            float v = 0.f;
            if ((unsigned)iy < 256u && (unsigned)ix < 256u)
                v = x[(size_t)(n * 3 + ch) * 65536 + iy * 256 + ix];
            xs[ch][r][cc] = v;
        }
        __syncthreads();
        int lr = 2 * (tid >> 7), lc = 2 * (tid & 127);
        double xd[3][4][4];
#pragma unroll
        for (int ci = 0; ci < 3; ++ci)
#pragma unroll
            for (int ky = 0; ky < 4; ++ky)
#pragma unroll
                for (int kx = 0; kx < 4; ++kx)
                    xd[ci][ky][kx] = (double)xs[ci][lr + ky][lc + kx];
#pragma unroll
        for (int co = 0; co < 16; ++co) {
            double acc = (double)bias[co];
            const double* wp = w64 + co * 48;
#pragma unroll
            for (int ci = 0; ci < 3; ++ci)
#pragma unroll
                for (int ky = 0; ky < 4; ++ky)
#pragma unroll
                    for (int kx = 0; kx < 4; ++kx)
                        acc = fma(xd[ci][ky][kx], wp[ci * 16 + ky * 4 + kx], acc);
            sums[co] += acc;
            sqs[co] = fma(acc, acc, sqs[co]);
        }
    }
    double val[32];
#pragma unroll
    for (int j = 0; j < 16; ++j) { val[j] = sums[j]; val[16 + j] = sqs[j]; }
#pragma unroll
    for (int o = 32; o; o >>= 1)
#pragma unroll
        for (int j = 0; j < 32; ++j) val[j] += __shfl_down(val[j], o);
    int wid = tid >> 6, lane = tid & 63;
    if (lane == 0)
#pragma unroll
        for (int j = 0; j < 32; ++j) lsw[wid][j] = val[j];
    __syncthreads();
    if (tid < 32) {
        double p = lsw[0][tid] + lsw[1][tid] + lsw[2][tid] + lsw[3][tid];
        partials[(size_t)(n * 32 + band) * 32 + tid] = p;
    }
}

// ---- fused conv1+BN1+ReLU -> conv2 -> h2 + stats. grid(64,64), block 512 ----
// BN1 consts hoisted to once/block (bit-identical); R20-form h1s layout.
__global__ void fused_conv2_k(const float* __restrict__ x, const double* __restrict__ w1_64,
                              const float* __restrict__ eb1, const float* __restrict__ eg1,
                              const float* __restrict__ ebt1, const double* __restrict__ w2_64,
                              const float* __restrict__ eb2, const double* __restrict__ stats,
                              float* __restrict__ h2, double* __restrict__ ph2) {
    __shared__ float xs[3][38][38];
    __shared__ float h1s[16][18][18];
    __shared__ double scd1[16], shd1[16];
    int tile = blockIdx.x, n = blockIdx.y, tid = threadIdx.x;
    int ty = tile >> 3, tx = tile & 7;
    int iyBase = 32 * ty - 3, ixBase = 32 * tx - 3;
    if (tid < 16) {
        double m = stats[tid] * (1.0 / 1048576.0);
        double var = stats[16 + tid] * (1.0 / 1048576.0) - m * m;
        double sc = (double)eg1[tid] / sqrt(var + EPS);
        scd1[tid] = sc;
        shd1[tid] = (double)ebt1[tid] - m * sc;
    }
    for (int idx = tid; idx < 3 * 38 * 38; idx += 512) {
        int ch = idx / 1444, rem = idx - ch * 1444, r = rem / 38, cc = rem - r * 38;
        int iy = iyBase + r, ix = ixBase + cc;
        float v = 0.f;
        if ((unsigned)iy < 256u && (unsigned)ix < 256u)
            v = x[(size_t)(n * 3 + ch) * 65536 + iy * 256 + ix];
        xs[ch][r][cc] = v;
    }
    __syncthreads();   // covers both scd1/shd1 and xs
    int hy0 = 16 * ty - 1, hx0 = 16 * tx - 1;
    for (int idx = tid; idx < 16 * 18 * 18; idx += 512) {
        int ci = idx / 324, rem = idx - ci * 324, r = rem / 18, cc = rem - r * 18;
        int hy = hy0 + r, hx = hx0 + cc;
        float val = 0.f;
        if ((unsigned)hy < 128u && (unsigned)hx < 128u) {
            double xd[3][4][4];
#pragma unroll
            for (int c3 = 0; c3 < 3; ++c3)
#pragma unroll
                for (int ky = 0; ky < 4; ++ky)
#pragma unroll
                    for (int kx = 0; kx < 4; ++kx)
                        xd[c3][ky][kx] = (double)xs[c3][2 * r + ky][2 * cc + kx];
            double acc = (double)eb1[ci];
            const double* wp = w1_64 + ci * 48;
#pragma unroll
            for (int c3 = 0; c3 < 3; ++c3)
#pragma unroll
                for (int ky = 0; ky < 4; ++ky)
#pragma unroll
                    for (int kx = 0; kx < 4; ++kx)
                        acc = fma(xd[c3][ky][kx], wp[c3 * 16 + ky * 4 + kx], acc);
            double v = fma(acc, scd1[ci], shd1[ci]);
            val = (float)(v > 0.0 ? v : 0.0);
        }
        h1s[ci][r][cc] = val;
    }
    __syncthreads();
    int s = tid & 63, ly = s >> 3, lx = s & 7;
    int cog = __builtin_amdgcn_readfirstlane((tid >> 6) * 4);  // 8 waves x 4 co
    double acc[4];
#pragma unroll
    for (int j = 0; j < 4; ++j) acc[j] = (double)eb2[cog + j];
    for (int ci = 0; ci < 16; ++ci) {
        double td[16];
#pragma unroll
        for (int ky = 0; ky < 4; ++ky)
#pragma unroll
            for (int kx = 0; kx < 4; ++kx)
                td[ky * 4 + kx] = (double)h1s[ci][2 * ly + ky][2 * lx + kx];
#pragma unroll
        for (int j = 0; j < 4; ++j) {
            const double* wp = w2_64 + ((cog + j) * 16 + ci) * 16;
#pragma unroll
            for (int k = 0; k < 16; ++k)
                acc[j] = fma(td[k], wp[k], acc[j]);
        }
    }
    int oy = 8 * ty + ly, ox = 8 * tx + lx;
    double s4[4], q4[4];
#pragma unroll
    for (int j = 0; j < 4; ++j) {
        float f = (float)acc[j];
        h2[(size_t)(n * 32 + cog + j) * 4096 + oy * 64 + ox] = f;
        double v = (double)f;
        s4[j] = v;
        q4[j] = v * v;
    }
#pragma unroll
    for (int o = 32; o; o >>= 1)
#pragma unroll
        for (int j = 0; j < 4; ++j) {
            s4[j] += __shfl_down(s4[j], o);
            q4[j] += __shfl_down(q4[j], o);
        }
    if (s == 0) {
        size_t blk = (size_t)(n * 64 + tile) * 64;
#pragma unroll
        for (int j = 0; j < 4; ++j) {
            ph2[blk + cog + j] = s4[j];
            ph2[blk + 32 + cog + j] = q4[j];
        }
    }
}

__device__ __forceinline__ void bn_consts(int tid, int C, const double* sum,
                                          const double* sq, const float* g,
                                          const float* b, double invCnt,
                                          double* scd, double* shd) {
    if (tid < C) {
        double m = sum[tid] * invCnt;
        double var = sq[tid] * invCnt - m * m;
        double sc = (double)g[tid] / sqrt(var + EPS);
        scd[tid] = sc;
        shd[tid] = (double)b[tid] - m * sc;
    }
}

// ---- conv3: BN2+ReLU(h2) staged -> z + stats. grid(16,64), block 512 ----
__global__ void conv3_k(const float* __restrict__ h2, const double* __restrict__ w3_64,
                        const float* __restrict__ bias, const float* __restrict__ eg2,
                        const float* __restrict__ ebt2, const double* __restrict__ sum2,
                        const double* __restrict__ sq2, float* __restrict__ z3,
                        double* __restrict__ pz) {
    __shared__ float hs[32][6][66];
    __shared__ double scd[32], shd[32];
    int c = blockIdx.x, n = blockIdx.y, tid = threadIdx.x;
    bn_consts(tid, 32, sum2, sq2, eg2, ebt2, 1.0 / 262144.0, scd, shd);
    __syncthreads();
    int iyBase = 4 * c - 1;
    for (int idx = tid; idx < 32 * 6 * 66; idx += 512) {
        int ch = idx / 396, rem = idx - ch * 396, r = rem / 66, cc = rem - r * 66;
        int iy = iyBase + r, ix = cc - 1;
        float val = 0.f;
        if ((unsigned)iy < 64u && (unsigned)ix < 64u) {
            double v = fma((double)h2[(size_t)(n * 32 + ch) * 4096 + iy * 64 + ix],
                           scd[ch], shd[ch]);
            val = v > 0.0 ? (float)v : 0.f;
        }
        hs[ch][r][cc] = val;
    }
    __syncthreads();
    int s = tid & 63;
    int oy = 2 * c + (s >> 5), ox = s & 31;
    int lr = 2 * (s >> 5), lc = 2 * ox;
    int cog = __builtin_amdgcn_readfirstlane((tid >> 6) * 8);
    double acc[8];
#pragma unroll
    for (int j = 0; j < 8; ++j) acc[j] = (double)bias[cog + j];
    for (int ci = 0; ci < 32; ++ci) {
        double td[16];
#pragma unroll
        for (int ky = 0; ky < 4; ++ky)
#pragma unroll
            for (int kx = 0; kx < 4; ++kx)
                td[ky * 4 + kx] = (double)hs[ci][lr + ky][lc + kx];
#pragma unroll
        for (int j = 0; j < 8; ++j) {
            const double* wp = w3_64 + ((cog + j) * 32 + ci) * 16;
#pragma unroll
            for (int k = 0; k < 16; ++k)
                acc[j] = fma(td[k], wp[k], acc[j]);
        }
    }
    double s8[8], q8[8];
#pragma unroll
    for (int j = 0; j < 8; ++j) {
        float f = (float)acc[j];
        z3[(size_t)(n * 64 + cog + j) * 1024 + oy * 32 + ox] = f;
        double v = (double)f;
        s8[j] = v;
        q8[j] = v * v;
    }
#pragma unroll
    for (int o = 32; o; o >>= 1)
#pragma unroll
        for (int j = 0; j < 8; ++j) {
            s8[j] += __shfl_down(s8[j], o);
            q8[j] += __shfl_down(q8[j], o);
        }
    if (s == 0) {
        size_t blk = (size_t)(n * 16 + c) * 128;
#pragma unroll
        for (int j = 0; j < 8; ++j) {
            pz[blk + cog + j] = s8[j];
            pz[blk + 64 + cog + j] = q8[j];
        }
    }
}

__device__ __forceinline__ float np_sum64(const float* a) {
    float r[8];
#pragma unroll
    for (int j = 0; j < 8; ++j) r[j] = a[j];
#pragma unroll
    for (int m = 1; m < 8; ++m)
#pragma unroll
        for (int j = 0; j < 8; ++j) r[j] += a[m * 8 + j];
    return ((r[0] + r[1]) + (r[2] + r[3])) + ((r[4] + r[5]) + (r[6] + r[7]));
}

__global__ void scc_k(const float* __restrict__ cb, float* __restrict__ scc) {
    int k = blockIdx.x * blockDim.x + threadIdx.x;
    if (k >= 512) return;
    const float* c = cb + (k << 6);
    float cc[64];
#pragma unroll
    for (int d = 0; d < 64; ++d) cc[d] = c[d] * c[d];
    scc[k] = np_sum64(cc);
}

// ---- VQ: 4-way k-chunk. grid(1024), block 256 ----
__global__ void vq_k(const float* __restrict__ zraw, const float* __restrict__ cb,
                     const float* __restrict__ scc, const float* __restrict__ eg3,
                     const float* __restrict__ ebt3, const double* __restrict__ sum3,
                     const double* __restrict__ sq3, float* __restrict__ quant,
                     double* __restrict__ lossAcc) {
    __shared__ double scd[64], shd[64];
    __shared__ float bfs[256];
    __shared__ int bis[256];
    bn_consts(threadIdx.x, 64, sum3, sq3, eg3, ebt3, 1.0 / 65536.0, scd, shd);
    __syncthreads();
    int chunk = threadIdx.x >> 6, pi = threadIdx.x & 63;
    int p = blockIdx.x * 64 + pi;
    int n = p >> 10, hw = p & 1023;
    const float* zp = zraw + (size_t)n * 65536 + hw;
    float z32[64], zz[64];
#pragma unroll
    for (int d = 0; d < 64; ++d) {
        double v = fma((double)zp[d * 1024], scd[d], shd[d]);
        z32[d] = v > 0.0 ? (float)v : 0.f;
        zz[d] = z32[d] * z32[d];
    }
    float sz = np_sum64(zz);
    int k0 = chunk << 7;
    float bestf = 3.4e38f;
    int bif = k0;
    for (int k = k0; k < k0 + 128; ++k) {
        const float* c = cb + (k << 6);
        float dot = 0.f;
#pragma unroll
        for (int d = 0; d < 64; ++d) dot = fmaf(z32[d], c[d], dot);
        float distf = (sz + scc[k]) - 2.f * dot;
        if (distf < bestf) { bestf = distf; bif = k; }
    }
    bfs[threadIdx.x] = bestf;
    bis[threadIdx.x] = bif;
    __syncthreads();
    if (chunk == 0) {
#pragma unroll
        for (int c4 = 1; c4 < 4; ++c4) {
            float v = bfs[c4 * 64 + pi];
            if (v < bestf) { bestf = v; bif = bis[c4 * 64 + pi]; }
        }
        const float* c = cb + (bif << 6);
        float* qp = quant + (size_t)n * 65536 + hw;
        double dist = 0.0;
#pragma unroll
        for (int d = 0; d < 64; ++d) {
            double diff = (double)z32[d] - (double)c[d];
            dist = fma(diff, diff, dist);
            qp[d * 1024] = c[d];
        }
        double s = dist;
#pragma unroll
        for (int o = 32; o; o >>= 1) s += __shfl_down(s, o);
        if (pi == 0) atomicAdd(lossAcc, s);
    }
}

__global__ void finalize_loss_k(const double* lossAcc, float* out, int idx) {
    if (threadIdx.x == 0 && blockIdx.x == 0)
        out[idx] = (float)(2.0 * (*lossAcc) / 4194304.0);
}

// ---- deconv1 + stats. grid(16,64), block 512: 8 waves x 4 co ----
__global__ void deconv1_k(const float* __restrict__ in, const float* __restrict__ w,
                          const float* __restrict__ bias, float* __restrict__ out,
                          double* __restrict__ pd1) {
    __shared__ float ls[64][4][34];
    int b = blockIdx.x, n = blockIdx.y, tid = threadIdx.x;
    int qy0 = 2 * b;
    for (int idx = tid; idx < 64 * 4 * 34; idx += 512) {
        int ch = idx / 136, rem = idx - ch * 136, r = rem / 34, cc = rem - r * 34;
        int iy = qy0 - 1 + r, ix = cc - 1;
        float v = 0.f;
        if ((unsigned)iy < 32u && (unsigned)ix < 32u)
            v = in[(size_t)(n * 64 + ch) * 1024 + iy * 32 + ix];
        ls[ch][r][cc] = v;
    }
    __syncthreads();
    int pt = tid & 63;
    int qy = qy0 + (pt >> 5), qx = pt & 31;
    int cog = (tid >> 6) * 4;
    int rb = qy - qy0;
    float acc[2][2][4];
#pragma unroll
    for (int dy = 0; dy < 2; ++dy)
#pragma unroll
        for (int dx = 0; dx < 2; ++dx)
#pragma unroll
            for (int j = 0; j < 4; ++j) acc[dy][dx][j] = bias[cog + j];
    for (int ci = 0; ci < 64; ++ci) {
        float v[3][3];
#pragma unroll
        for (int ry = 0; ry < 3; ++ry)
#pragma unroll
            for (int rx = 0; rx < 3; ++rx)
                v[ry][rx] = ls[ci][rb + ry][qx + rx];
#pragma unroll
        for (int j = 0; j < 4; ++j) {
            const float* wp = w + ((cog + j) * 64 + ci) * 16;
            acc[0][0][j] += v[0][0]*wp[0] + v[0][1]*wp[2] + v[1][0]*wp[8]  + v[1][1]*wp[10];
            acc[0][1][j] += v[0][1]*wp[1] + v[0][2]*wp[3] + v[1][1]*wp[9]  + v[1][2]*wp[11];
            acc[1][0][j] += v[1][0]*wp[4] + v[1][1]*wp[6] + v[2][0]*wp[12] + v[2][1]*wp[14];
            acc[1][1][j] += v[1][1]*wp[5] + v[1][2]*wp[7] + v[2][1]*wp[13] + v[2][2]*wp[15];
        }
    }
    double s4[4], q4[4];
#pragma unroll
    for (int j = 0; j < 4; ++j) { s4[j] = 0.0; q4[j] = 0.0; }
#pragma unroll
    for (int dy = 0; dy < 2; ++dy)
#pragma unroll
        for (int dx = 0; dx < 2; ++dx)
#pragma unroll
            for (int j = 0; j < 4; ++j) {
                float f = acc[dy][dx][j];
                out[(size_t)(n * 32 + cog + j) * 4096 + (2*qy+dy) * 64 + 2*qx+dx] = f;
                double v = (double)f;
                s4[j] += v;
                q4[j] = fma(v, v, q4[j]);
            }
#pragma unroll
    for (int o = 32; o; o >>= 1)
#pragma unroll
        for (int j = 0; j < 4; ++j) {
            s4[j] += __shfl_down(s4[j], o);
            q4[j] += __shfl_down(q4[j], o);
        }
    if (pt == 0) {
        size_t blk = (size_t)(n * 16 + b) * 64;
#pragma unroll
        for (int j = 0; j < 4; ++j) {
            pd1[blk + cog + j] = s4[j];
            pd1[blk + 32 + cog + j] = q4[j];
        }
    }
}

// ---- deconv2: BN4+ReLU(d1) staged + stats. grid(64,64), block 512 ----
__global__ void deconv2_k(const float* __restrict__ in, const float* __restrict__ w,
                          const float* __restrict__ bias, const float* __restrict__ g,
                          const float* __restrict__ bt, const double* __restrict__ sum,
                          const double* __restrict__ sq, float* __restrict__ out,
                          double* __restrict__ pd2) {
    __shared__ float ls[32][3][66];
    __shared__ double scd[32], shd[32];
    int b = blockIdx.x, n = blockIdx.y, tid = threadIdx.x;
    bn_consts(tid, 32, sum, sq, g, bt, 1.0 / 262144.0, scd, shd);
    __syncthreads();
    for (int idx = tid; idx < 32 * 3 * 66; idx += 512) {
        int ch = idx / 198, rem = idx - ch * 198, r = rem / 66, cc = rem - r * 66;
        int iy = b - 1 + r, ix = cc - 1;
        float val = 0.f;
        if ((unsigned)iy < 64u && (unsigned)ix < 64u) {
            double v = fma((double)in[(size_t)(n * 32 + ch) * 4096 + iy * 64 + ix],
                           scd[ch], shd[ch]);
            val = v > 0.0 ? (float)v : 0.f;
        }
        ls[ch][r][cc] = val;
    }
    __syncthreads();
    int qx = tid & 63;
    int cog = (tid >> 6) * 2;
    float acc[2][2][2];
#pragma unroll
    for (int dy = 0; dy < 2; ++dy)
#pragma unroll
        for (int dx = 0; dx < 2; ++dx)
#pragma unroll
            for (int j = 0; j < 2; ++j) acc[dy][dx][j] = bias[cog + j];
    for (int ci = 0; ci < 32; ++ci) {
        float v[3][3];
#pragma unroll
        for (int ry = 0; ry < 3; ++ry)
#pragma unroll
            for (int rx = 0; rx < 3; ++rx)
                v[ry][rx] = ls[ci][ry][qx + rx];
#pragma unroll
        for (int j = 0; j < 2; ++j) {
            const float* wp = w + ((cog + j) * 32 + ci) * 16;
            acc[0][0][j] += v[0][0]*wp[0] + v[0][1]*wp[2] + v[1][0]*wp[8]  + v[1][1]*wp[10];
            acc[0][1][j] += v[0][1]*wp[1] + v[0][2]*wp[3] + v[1][1]*wp[9]  + v[1][2]*wp[11];
            acc[1][0][j] += v[1][0]*wp[4] + v[1][1]*wp[6] + v[2][0]*wp[12] + v[2][1]*wp[14];
            acc[1][1][j] += v[1][1]*wp[5] + v[1][2]*wp[7] + v[2][1]*wp[13] + v[2][2]*wp[15];
        }
    }
    double s2[2], q2[2];
#pragma unroll
    for (int j = 0; j < 2; ++j) { s2[j] = 0.0; q2[j] = 0.0; }
#pragma unroll
    for (int dy = 0; dy < 2; ++dy)
#pragma unroll
        for (int dx = 0; dx < 2; ++dx)
#pragma unroll
            for (int j = 0; j < 2; ++j) {
                float f = acc[dy][dx][j];
                out[(size_t)(n * 16 + cog + j) * 16384 + (2*b+dy) * 128 + 2*qx+dx] = f;
                double v = (double)f;
                s2[j] += v;
                q2[j] = fma(v, v, q2[j]);
            }
#pragma unroll
    for (int o = 32; o; o >>= 1)
#pragma unroll
        for (int j = 0; j < 2; ++j) {
            s2[j] += __shfl_down(s2[j], o);
            q2[j] += __shfl_down(q2[j], o);
        }
    if (qx == 0) {
        size_t blk = (size_t)(n * 64 + b) * 32;
#pragma unroll
        for (int j = 0; j < 2; ++j) {
            pd2[blk + cog + j] = s2[j];
            pd2[blk + 16 + cog + j] = q2[j];
        }
    }
}

// ---- deconv3: BN5+ReLU(d2) staged -> raw into d_out + stats. grid(64,64),256 ----
__global__ void deconv3_k(const float* __restrict__ in, const float* __restrict__ w,
                          const float* __restrict__ bias, const float* __restrict__ g,
                          const float* __restrict__ bt, const double* __restrict__ sum,
                          const double* __restrict__ sq, float* __restrict__ out,
                          double* __restrict__ pd3) {
    __shared__ float ls[16][4][130];
    __shared__ double scd[16], shd[16];
    __shared__ double lsw[4][6];
    int b = blockIdx.x, n = blockIdx.y, tid = threadIdx.x;
    bn_consts(tid, 16, sum, sq, g, bt, 1.0 / 1048576.0, scd, shd);
    __syncthreads();
    int qy0 = 2 * b;
    for (int idx = tid; idx < 16 * 4 * 130; idx += 256) {
        int ch = idx / 520, rem = idx - ch * 520, r = rem / 130, cc = rem - r * 130;
        int iy = qy0 - 1 + r, ix = cc - 1;
        float val = 0.f;
        if ((unsigned)iy < 128u && (unsigned)ix < 128u) {
            double v = fma((double)in[(size_t)(n * 16 + ch) * 16384 + iy * 128 + ix],
                           scd[ch], shd[ch]);
            val = v > 0.0 ? (float)v : 0.f;
        }
        ls[ch][r][cc] = val;
    }
    __syncthreads();
    int qy = qy0 + (tid >> 7), qx = tid & 127;
    int rb = qy - qy0;
    float acc[2][2][3];
#pragma unroll
    for (int dy = 0; dy < 2; ++dy)
#pragma unroll
        for (int dx = 0; dx < 2; ++dx)
#pragma unroll
            for (int j = 0; j < 3; ++j) acc[dy][dx][j] = bias[j];
    for (int ci = 0; ci < 16; ++ci) {
        float v[3][3];
#pragma unroll
        for (int ry = 0; ry < 3; ++ry)
#pragma unroll
            for (int rx = 0; rx < 3; ++rx)
                v[ry][rx] = ls[ci][rb + ry][qx + rx];
#pragma unroll
        for (int j = 0; j < 3; ++j) {
            const float* wp = w + (j * 16 + ci) * 16;
            acc[0][0][j] += v[0][0]*wp[0] + v[0][1]*wp[2] + v[1][0]*wp[8]  + v[1][1]*wp[10];
            acc[0][1][j] += v[0][1]*wp[1] + v[0][2]*wp[3] + v[1][1]*wp[9]  + v[1][2]*wp[11];
            acc[1][0][j] += v[1][0]*wp[4] + v[1][1]*wp[6] + v[2][0]*wp[12] + v[2][1]*wp[14];
            acc[1][1][j] += v[1][1]*wp[5] + v[1][2]*wp[7] + v[2][1]*wp[13] + v[2][2]*wp[15];
        }
    }
    double s3[3], q3[3];
#pragma unroll
    for (int j = 0; j < 3; ++j) { s3[j] = 0.0; q3[j] = 0.0; }
#pragma unroll
    for (int dy = 0; dy < 2; ++dy)
#pragma unroll
        for (int dx = 0; dx < 2; ++dx)
#pragma unroll
            for (int j = 0; j < 3; ++j) {
                float f = acc[dy][dx][j];
                out[(size_t)(n * 3 + j) * 65536 + (2*qy+dy) * 256 + 2*qx+dx] = f;
                double v = (double)f;
                s3[j] += v;
                q3[j] = fma(v, v, q3[j]);
            }
#pragma unroll
    for (int o = 32; o; o >>= 1)
#pragma unroll
        for (int j = 0; j < 3; ++j) {
            s3[j] += __shfl_down(s3[j], o);
            q3[j] += __shfl_down(q3[j], o);
        }
    int wid = tid >> 6, lane = tid & 63;
    if (lane == 0)
#pragma unroll
        for (int j = 0; j < 3; ++j) { lsw[wid][j] = s3[j]; lsw[wid][3 + j] = q3[j]; }
    __syncthreads();
    if (tid < 6) {
        double p = lsw[0][tid] + lsw[1][tid] + lsw[2][tid] + lsw[3][tid];
        pd3[(size_t)(n * 64 + b) * 6 + tid] = p;
    }
}

// ---- final BN + tanh IN PLACE on d_out; constants hoisted per block ----
__global__ void bn_tanh_k(float* __restrict__ y, const double* __restrict__ sum,
                          const double* __restrict__ sq, const float* __restrict__ g,
                          const float* __restrict__ b, int HW, double invCnt) {
    __shared__ double cst[2];
    int c = blockIdx.y, n = blockIdx.z, C = gridDim.y;
    if (threadIdx.x == 0) {
        double m = sum[c] * invCnt;
        double var = sq[c] * invCnt - m * m;
        double sc = (double)g[c] / sqrt(var + EPS);
        cst[0] = sc;
        cst[1] = (double)b[c] - m * sc;
    }
    __syncthreads();
    int hw = blockIdx.x * blockDim.x + threadIdx.x;
    size_t i = (size_t)(n * C + c) * HW + hw;
    y[i] = tanhf((float)fma((double)y[i], cst[0], cst[1]));
}

extern "C" void kernel_launch(void* const* d_in, const int* in_sizes, int n_in,
                              void* d_out, int out_size, void* d_ws, size_t ws_size,
                              hipStream_t stream) {
    const float* x   = (const float*)d_in[0];
    const float* cb  = (const float*)d_in[1];
    const float* eW1 = (const float*)d_in[2];
    const float* eb1 = (const float*)d_in[3];
    const float* eg1 = (const float*)d_in[4];
    const float* ebt1= (const float*)d_in[5];
    const float* eW2 = (const float*)d_in[6];
    const float* eb2 = (const float*)d_in[7];
    const float* eg2 = (const float*)d_in[8];
    const float* ebt2= (const float*)d_in[9];
    const float* eW3 = (const float*)d_in[10];
    const float* eb3 = (const float*)d_in[11];
    const float* eg3 = (const float*)d_in[12];
    const float* ebt3= (const float*)d_in[13];
    const float* dW1 = (const float*)d_in[14];
    const float* db1 = (const float*)d_in[15];
    const float* dg1 = (const float*)d_in[16];
    const float* dbt1= (const float*)d_in[17];
    const float* dW2 = (const float*)d_in[18];
    const float* db2 = (const float*)d_in[19];
    const float* dg2 = (const float*)d_in[20];
    const float* dbt2= (const float*)d_in[21];
    const float* dW3 = (const float*)d_in[22];
    const float* db3 = (const float*)d_in[23];
    const float* dg3 = (const float*)d_in[24];
    const float* dbt3= (const float*)d_in[25];

    float* out = (float*)d_out;
    char* ws = (char*)d_ws;
    float* h2    = (float*)ws;                        // [0, 33.5M)
    float* z     = (float*)(ws + 33554432);           // [33.5M, 50.3M)
    float* quant = (float*)(ws + 50331648);           // [50.3M, 67.1M)
    float* d1    = (float*)(ws + 67108864);           // [67.1M, 100.7M)
    float* d2    = (float*)ws;                        // [0, 67.1M)
    double* partials = (double*)ws;                   // conv1, dead pre-h2
    double* w64  = (double*)(ws + 67108864);          // dead before d1
    double* w1_64 = w64;
    double* w2_64 = w64 + 768;
    double* w3_64 = w64 + 768 + 8192;
    double* ph2  = (double*)(ws + 50331648);          // 2MB, dead pre-vq-quant
    double* pz   = (double*)(ws + 52428800);          // 1MB, dead pre-vq-quant
    double* pd1  = (double*)ws;                       // 512KB, dead pre-d2
    double* pd2  = (double*)(ws + 100663296);         // 1MB, above d1 (free)
    double* pd3  = (double*)(ws + 67108864);          // 192KB, free post-deconv2
    double* stats = (double*)(ws + 117440512);        // 327 doubles
    double* lossAcc = stats + 326;
    float* scc   = (float*)(ws + 117443200);          // 512 f32
    dim3 B(256), B2(512);

    zero_stats_k<<<2, B, 0, stream>>>(stats, 327);
    scc_k<<<2, B, 0, stream>>>(cb, scc);
    convert_w_k<<<163, B, 0, stream>>>(eW1, eW2, eW3, w64);

    // encoder
    conv1_stats_k<<<dim3(32, 64), B, 0, stream>>>(x, w1_64, eb1, partials);
    reduce_p_k<<<32, B, 0, stream>>>(partials, 2048, 32, stats);
    fused_conv2_k<<<dim3(64, 64), B2, 0, stream>>>(x, w1_64, eb1, eg1, ebt1, w2_64,
                                                   eb2, stats, h2, ph2);
    reduce_p_k<<<64, B, 0, stream>>>(ph2, 4096, 64, stats + 32);
    conv3_k<<<dim3(16, 64), B2, 0, stream>>>(h2, w3_64, eb3, eg2, ebt2,
                                             stats + 32, stats + 64, z, pz);
    reduce_p_k<<<128, B, 0, stream>>>(pz, 1024, 128, stats + 96);
    vq_k<<<1024, B, 0, stream>>>(z, cb, scc, eg3, ebt3, stats + 96, stats + 160,
                                 quant, lossAcc);
    finalize_loss_k<<<1, 64, 0, stream>>>(lossAcc, out, out_size - 1);

    // decoder
    deconv1_k<<<dim3(16, 64), B2, 0, stream>>>(quant, dW1, db1, d1, pd1);
    reduce_p_k<<<64, B, 0, stream>>>(pd1, 1024, 64, stats + 224);
    deconv2_k<<<dim3(64, 64), B2, 0, stream>>>(d1, dW2, db2, dg1, dbt1,
                                               stats + 224, stats + 256, d2, pd2);
    reduce_p_k<<<32, B, 0, stream>>>(pd2, 4096, 32, stats + 288);
    deconv3_k<<<dim3(64, 64), B, 0, stream>>>(d2, dW3, db3, dg2, dbt2,
                                              stats + 288, stats + 304, out, pd3);
    reduce_p_k<<<6, B, 0, stream>>>(pd3, 4096, 6, stats + 320);
    bn_tanh_k<<<dim3(256, 3, 64), B, 0, stream>>>(out, stats + 320, stats + 323,
                                                  dg3, dbt3, 65536, 1.0 / 4194304.0);
}